// Round 17
// baseline (3085.048 us; speedup 1.0000x reference)
//
#include <hip/hip_runtime.h>
#include <stdint.h>

#define EMBED  512
#define HIDDEN 512
#define VOCAB  32000
#define BATCH  64
#define NPIX   196
#define MAXLEN 32
#define NBLK   256
#define NTHR   512
#define NGRP   16       // 16 groups x 16 blocks (barrier tree)

typedef float f32x4 __attribute__((ext_vector_type(4)));
typedef short bf16x8 __attribute__((ext_vector_type(8)));
typedef unsigned short ushort_t;
typedef unsigned long long u64;

// ---------- helpers ----------
__device__ __forceinline__ u64 pack_key(float v, int idx) {
    unsigned u = __float_as_uint(v);
    u = (u & 0x80000000u) ? ~u : (u | 0x80000000u);   // monotone sortable map
    return ((u64)u << 32) | (unsigned)(~(unsigned)idx); // smaller idx wins ties
}
__device__ __forceinline__ ushort_t f2bf(float x) {           // round-to-nearest-even
    unsigned u = __float_as_uint(x);
    unsigned r = (u + 0x7fffu + ((u >> 16) & 1u)) >> 16;
    return (ushort_t)r;
}
__device__ __forceinline__ float bf2f(ushort_t h) {
    return __uint_as_float(((unsigned)h) << 16);
}
__device__ __forceinline__ void cst32(unsigned* p, unsigned v) {
    __hip_atomic_store(p, v, __ATOMIC_RELAXED, __HIP_MEMORY_SCOPE_AGENT);
}
__device__ __forceinline__ u64 cld64(const u64* p) {
    return __hip_atomic_load(p, __ATOMIC_RELAXED, __HIP_MEMORY_SCOPE_AGENT);
}
// 3-way split: 8 fp32 -> bf16 H1+H2+H3 (residual ~2^-27)
__device__ __forceinline__ void split3_8(f32x4 a, f32x4 b,
                                         bf16x8& h1, bf16x8& h2, bf16x8& h3) {
    union { ushort_t s[8]; bf16x8 v; } U1, U2, U3;
#pragma unroll
    for (int e = 0; e < 4; ++e) {
        float v0 = a[e];
        ushort_t x1 = f2bf(v0); float r1 = v0 - bf2f(x1);
        ushort_t x2 = f2bf(r1); float r2 = r1 - bf2f(x2);
        U1.s[e] = x1; U2.s[e] = x2; U3.s[e] = f2bf(r2);
        float v1 = b[e];
        ushort_t y1 = f2bf(v1); float s1 = v1 - bf2f(y1);
        ushort_t y2 = f2bf(s1); float s2 = s1 - bf2f(y2);
        U1.s[4 + e] = y1; U2.s[4 + e] = y2; U3.s[4 + e] = f2bf(s2);
    }
    h1 = U1.v; h2 = U2.v; h3 = U3.v;
}

// ---------- tree grid barrier (R10-proven; R14 backoff) ----------
__device__ __forceinline__ void grid_barrier(unsigned* barws, int k, bool fence) {
    __syncthreads();
    if (threadIdx.x == 0) {
        const int grp = blockIdx.x >> 4;
        const bool leader = (blockIdx.x & 15) == 0;
        unsigned* gc = barws + (k * NGRP + grp) * 16;
        unsigned* rc = barws + 16384 + k * 16;
        unsigned* gf = barws + 17408 + (k * NGRP + grp) * 16;
        if (fence) __threadfence();
        else asm volatile("s_waitcnt vmcnt(0)" ::: "memory");
        if (!leader) {
            __hip_atomic_fetch_add(gc, 1u, __ATOMIC_RELAXED, __HIP_MEMORY_SCOPE_AGENT);
            while (__hip_atomic_fetch_add(gf, 0u, __ATOMIC_RELAXED, __HIP_MEMORY_SCOPE_AGENT) == 0u)
                __builtin_amdgcn_s_sleep(32);
        } else {
            while (__hip_atomic_fetch_add(gc, 0u, __ATOMIC_RELAXED, __HIP_MEMORY_SCOPE_AGENT) < 15u)
                __builtin_amdgcn_s_sleep(8);
            __hip_atomic_fetch_add(rc, 1u, __ATOMIC_RELAXED, __HIP_MEMORY_SCOPE_AGENT);
            while (__hip_atomic_fetch_add(rc, 0u, __ATOMIC_RELAXED, __HIP_MEMORY_SCOPE_AGENT) < (unsigned)NGRP)
                __builtin_amdgcn_s_sleep(8);
            __hip_atomic_fetch_add(gf, 1u, __ATOMIC_RELAXED, __HIP_MEMORY_SCOPE_AGENT);
        }
        asm volatile("" ::: "memory");
    }
    __syncthreads();
}

__global__ void ws_init(unsigned* barws, u64* kslab) {
    const int i = blockIdx.x * 256 + threadIdx.x;
    if (i < 33792) barws[i] = 0u;
    if (i < 31 * 1024) kslab[i] = 0ull;      // 31 steps x 64 rows x 16-u64 stride
}

// ---------- the whole decode, one persistent kernel ----------
// gates phase: MFMA with 3-way split (6 products, rel err ~2e-8 == fp32-ordering
// noise class) — 64 blocks, 32-col tiles = 4 gates x 8 units, split-K x4.
// fc phase: R15-verified bf16 hi/lo (H1/H2) 3-product MFMA.
__global__ __launch_bounds__(512, 2) void decode_all(
    const float* __restrict__ enc,
    const int*   __restrict__ captions,
    const float* __restrict__ emb,
    const float* __restrict__ W_ih, const float* __restrict__ b_ih,
    const float* __restrict__ W_hh, const float* __restrict__ b_hh,
    const float* __restrict__ W_fc, const float* __restrict__ b_fc,
    const float* __restrict__ W_init_h, const float* __restrict__ b_init_h,
    const float* __restrict__ W_init_c, const float* __restrict__ b_init_c,
    float* __restrict__ out,
    float* __restrict__ cbuf,       // [64][512] c-state, block-owned slices
    unsigned* __restrict__ hhis,    // [32][64][256] packed 2xbf16 H1 slabs
    unsigned* __restrict__ hlos,    // [32][64][256] packed 2xbf16 H2 slabs
    unsigned* __restrict__ hxs,     // [32][64][256] packed 2xbf16 H3 slabs
    u64* __restrict__ kslab,        // [31][64][16] argmax keys (pre-zeroed)
    ushort_t* __restrict__ Whi, ushort_t* __restrict__ Wlo,
    unsigned* __restrict__ barws)
{
    __shared__ __align__(16) float smem[24576];       // 96 KB (fc dump / gates dump)
    __shared__ u64 kredl[128];                        // fc key merge
    __shared__ int ltoks[BATCH];

    const int blk = blockIdx.x, tid = threadIdx.x;
    const int lane = tid & 63, w = tid >> 6;
    const int r16 = lane & 15, g = lane >> 4;

    // ---- one-time: wsplit W_fc -> Whi/Wlo ----
    {
        const int nt4 = VOCAB * EMBED / 4;
        for (int i = blk * NTHR + tid; i < nt4; i += NBLK * NTHR) {
            f32x4 wv = ((const f32x4*)W_fc)[i];
            ushort_t hi[4], lo[4];
#pragma unroll
            for (int e = 0; e < 4; ++e) {
                hi[e] = f2bf(wv[e]);
                lo[e] = f2bf(wv[e] - bf2f(hi[e]));
            }
            *(uint64_t*)&Whi[i * 4] = *(const uint64_t*)hi;
            *(uint64_t*)&Wlo[i * 4] = *(const uint64_t*)lo;
        }
    }

    // ---- one-time: init (blocks 0..63): summary, h0 -> slab0 (3 components), c0 ----
    if (blk < BATCH) {
        const int b = blk;
        {
            float s = 0.f;
            const float* p = enc + (size_t)b * NPIX * HIDDEN + tid;
            for (int px = 0; px < NPIX; ++px) s += p[(size_t)px * HIDDEN];
            smem[tid] = s * (1.0f / NPIX);
        }
        __syncthreads();
        {
            const int j = tid;
            const f32x4* wh = (const f32x4*)(W_init_h + (size_t)j * HIDDEN);
            const f32x4* wc = (const f32x4*)(W_init_c + (size_t)j * HIDDEN);
            float ah = 0.f, ac = 0.f;
            for (int k4 = 0; k4 < HIDDEN / 4; ++k4) {
                f32x4 s4 = *(const f32x4*)&smem[k4 * 4];
                f32x4 a = wh[k4], cc = wc[k4];
                ah += s4[0]*a[0] + s4[1]*a[1] + s4[2]*a[2] + s4[3]*a[3];
                ac += s4[0]*cc[0] + s4[1]*cc[1] + s4[2]*cc[2] + s4[3]*cc[3];
            }
            ah += b_init_h[j];
            cbuf[b * HIDDEN + j] = ac + b_init_c[j];
            ushort_t c1 = f2bf(ah); float r1 = ah - bf2f(c1);
            ushort_t c2 = f2bf(r1); float r2 = r1 - bf2f(c2);
            ushort_t c3 = f2bf(r2);
            unsigned p1 = c1, p2 = c2, p3 = c3;
            unsigned q1 = __shfl_xor(p1, 1, 64);
            unsigned q2 = __shfl_xor(p2, 1, 64);
            unsigned q3 = __shfl_xor(p3, 1, 64);
            if ((j & 1) == 0) {   // plain stores; fenced barrier 0 publishes
                hhis[b * 256 + (j >> 1)] = p1 | (q1 << 16);
                hlos[b * 256 + (j >> 1)] = p2 | (q2 << 16);
                hxs [b * 256 + (j >> 1)] = p3 | (q3 << 16);
            }
        }
        f32x4* o4 = (f32x4*)(out + (size_t)b * MAXLEN * VOCAB);
        f32x4 z = {0.f, 0.f, 0.f, 0.f};
        for (int i = tid; i < VOCAB / 4; i += NTHR) __builtin_nontemporal_store(z, &o4[i]);
    }
    grid_barrier(barws, 0, true);

    // ======== 31 decode steps ========
    for (int t = 0; t < MAXLEN - 1; ++t) {
        const unsigned* hin_1 = hhis + (size_t)t * 16384;          // h(t) H1
        const unsigned* hin_2 = hlos + (size_t)t * 16384;          // H2
        const unsigned* hin_3 = hxs  + (size_t)t * 16384;          // H3
        unsigned* hout_1 = hhis + (size_t)(t + 1) * 16384;         // h(t+1)
        unsigned* hout_2 = hlos + (size_t)(t + 1) * 16384;
        unsigned* hout_3 = hxs  + (size_t)(t + 1) * 16384;

        // ---------- gates phase (blocks 0..63): 6-product MFMA ----------
        if (blk < 64) {
            const int gb = blk;
            if (tid < BATCH) {
                int tok;
                if (t == 0) tok = captions[tid * MAXLEN];
                else {
                    u64 km = cld64(kslab + (size_t)(t - 1) * 1024 + tid * 16);
                    tok = (int)(~(unsigned)(km & 0xffffffffull));
                }
                ltoks[tid] = tok;
            }
            __syncthreads();

            f32x4 acc[4][2];
#pragma unroll
            for (int i = 0; i < 4; ++i) { acc[i][0] = (f32x4){0,0,0,0}; acc[i][1] = (f32x4){0,0,0,0}; }

            if (w < 4) {
                const int ks = w;               // K slice: [ks*256, ks*256+256)
                int tok4[4];
#pragma unroll
                for (int mt = 0; mt < 4; ++mt) tok4[mt] = ltoks[mt * 16 + r16];
                int jrow[2];
#pragma unroll
                for (int nt = 0; nt < 2; ++nt) {
                    const int c = nt * 16 + r16;
                    jrow[nt] = (c >> 3) * HIDDEN + gb * 8 + (c & 7);
                }
#pragma unroll
                for (int kb = 0; kb < 8; ++kb) {
                    const int kk = ks * 256 + kb * 32 + g * 8;
                    bf16x8 A1[4], A2[4], A3[4], B1[2], B2[2], B3[2];
                    if (ks < 2) {               // x half: emb fp32, 3-way split
#pragma unroll
                        for (int mt = 0; mt < 4; ++mt) {
                            const float* xp = emb + (size_t)tok4[mt] * EMBED + kk;
                            split3_8(*(const f32x4*)xp, *(const f32x4*)(xp + 4),
                                     A1[mt], A2[mt], A3[mt]);
                        }
#pragma unroll
                        for (int nt = 0; nt < 2; ++nt) {
                            const float* wp = W_ih + (size_t)jrow[nt] * EMBED + kk;
                            split3_8(*(const f32x4*)wp, *(const f32x4*)(wp + 4),
                                     B1[nt], B2[nt], B3[nt]);
                        }
                    } else {                    // h half: H1/H2/H3 slabs
                        const int kh2 = (kk - 512) >> 1;
#pragma unroll
                        for (int mt = 0; mt < 4; ++mt) {
                            A1[mt] = *(const bf16x8*)(hin_1 + (size_t)(mt * 16 + r16) * 256 + kh2);
                            A2[mt] = *(const bf16x8*)(hin_2 + (size_t)(mt * 16 + r16) * 256 + kh2);
                            A3[mt] = *(const bf16x8*)(hin_3 + (size_t)(mt * 16 + r16) * 256 + kh2);
                        }
#pragma unroll
                        for (int nt = 0; nt < 2; ++nt) {
                            const float* wp = W_hh + (size_t)jrow[nt] * HIDDEN + (kk - 512);
                            split3_8(*(const f32x4*)wp, *(const f32x4*)(wp + 4),
                                     B1[nt], B2[nt], B3[nt]);
                        }
                    }
#pragma unroll
                    for (int mt = 0; mt < 4; ++mt)
#pragma unroll
                        for (int nt = 0; nt < 2; ++nt) {
                            acc[mt][nt] = __builtin_amdgcn_mfma_f32_16x16x32_bf16(A3[mt], B1[nt], acc[mt][nt], 0, 0, 0);
                            acc[mt][nt] = __builtin_amdgcn_mfma_f32_16x16x32_bf16(A1[mt], B3[nt], acc[mt][nt], 0, 0, 0);
                            acc[mt][nt] = __builtin_amdgcn_mfma_f32_16x16x32_bf16(A2[mt], B2[nt], acc[mt][nt], 0, 0, 0);
                            acc[mt][nt] = __builtin_amdgcn_mfma_f32_16x16x32_bf16(A2[mt], B1[nt], acc[mt][nt], 0, 0, 0);
                            acc[mt][nt] = __builtin_amdgcn_mfma_f32_16x16x32_bf16(A1[mt], B2[nt], acc[mt][nt], 0, 0, 0);
                            acc[mt][nt] = __builtin_amdgcn_mfma_f32_16x16x32_bf16(A1[mt], B1[nt], acc[mt][nt], 0, 0, 0);
                        }
                }
            }
            if (w >= 1 && w < 4) {
                float* slab = smem + (w - 1) * 2048;
#pragma unroll
                for (int mt = 0; mt < 4; ++mt)
#pragma unroll
                    for (int nt = 0; nt < 2; ++nt)
#pragma unroll
                        for (int reg = 0; reg < 4; ++reg)
                            slab[((mt * 2 + nt) * 4 + reg) * 64 + lane] = acc[mt][nt][reg];
            }
            __syncthreads();
            if (w == 0) {
#pragma unroll
                for (int mt = 0; mt < 4; ++mt)
#pragma unroll
                    for (int nt = 0; nt < 2; ++nt)
#pragma unroll
                        for (int reg = 0; reg < 4; ++reg) {
                            const int idx = ((mt * 2 + nt) * 4 + reg) * 64 + lane;
                            acc[mt][nt][reg] += smem[idx] + smem[2048 + idx] + smem[4096 + idx];
                        }
                float bias[2];
#pragma unroll
                for (int nt = 0; nt < 2; ++nt) {
                    const int c = nt * 16 + r16;
                    const int j = (c >> 3) * HIDDEN + gb * 8 + (c & 7);
                    bias[nt] = b_ih[j] + b_hh[j];
                }
#pragma unroll
                for (int mt = 0; mt < 4; ++mt)
#pragma unroll
                    for (int reg = 0; reg < 4; ++reg) {
                        float v0 = acc[mt][0][reg] + bias[0];   // gate i (r16<8) / f (r16>=8)
                        float v1 = acc[mt][1][reg] + bias[1];   // gate g (r16<8) / o (r16>=8)
                        float p0 = __shfl_xor(v0, 8, 64);
                        float p1 = __shfl_xor(v1, 8, 64);
                        unsigned w1 = 0, w2 = 0, w3 = 0;
                        const int b = mt * 16 + g * 4 + reg;
                        if (r16 < 8) {
                            const int u = gb * 8 + r16;
                            float i_ = 1.f / (1.f + expf(-v0));
                            float f_ = 1.f / (1.f + expf(-p0));
                            float g_ = tanhf(v1);
                            float o_ = 1.f / (1.f + expf(-p1));
                            float cv = cbuf[b * HIDDEN + u];
                            float c2 = f_ * cv + i_ * g_;
                            float h2 = o_ * tanhf(c2);
                            cbuf[b * HIDDEN + u] = c2;
                            ushort_t c1s = f2bf(h2); float r1 = h2 - bf2f(c1s);
                            ushort_t c2s = f2bf(r1); float r2 = r1 - bf2f(c2s);
                            ushort_t c3s = f2bf(r2);
                            w1 = c1s; w2 = c2s; w3 = c3s;
                        }
                        unsigned q1 = __shfl_xor(w1, 1, 64);
                        unsigned q2 = __shfl_xor(w2, 1, 64);
                        unsigned q3 = __shfl_xor(w3, 1, 64);
                        if (r16 < 8 && (r16 & 1) == 0) {
                            const int u = gb * 8 + r16;
                            cst32(hout_1 + b * 256 + (u >> 1), w1 | (q1 << 16));
                            cst32(hout_2 + b * 256 + (u >> 1), w2 | (q2 << 16));
                            cst32(hout_3 + b * 256 + (u >> 1), w3 | (q3 << 16));
                        }
                    }
            }
        }
        grid_barrier(barws, 1 + 2 * t, false);

        // ---------- FC phase (blocks 0..249; 2 tiles, 4-wave split-K; R15-verified) ----------
        const int tsel = w >> 2, ks = w & 3;
        const int tileIdx = blk * 2 + tsel;
        const int n0 = tileIdx * 64;
        if (blk < 250) {
            f32x4 acc[4][4];
#pragma unroll
            for (int i = 0; i < 4; ++i)
#pragma unroll
                for (int jj = 0; jj < 4; ++jj) acc[i][jj] = (f32x4){0.f, 0.f, 0.f, 0.f};

            const ushort_t* hb = Whi + (size_t)(n0 + r16) * EMBED + ks * 128 + g * 8;
            const ushort_t* lb = Wlo + (size_t)(n0 + r16) * EMBED + ks * 128 + g * 8;

#pragma unroll
            for (int kb = 0; kb < 4; ++kb) {
                const int ko = kb * 32;
                const int w32 = ks * 64 + kb * 16 + g * 4;   // u32 index of A-frag
                bf16x8 Ah[4], Al[4], Bh[4], Bl[4];
#pragma unroll
                for (int mt = 0; mt < 4; ++mt) {
                    Ah[mt] = *(const bf16x8*)(hout_1 + (size_t)(mt * 16 + r16) * 256 + w32);
                    Al[mt] = *(const bf16x8*)(hout_2 + (size_t)(mt * 16 + r16) * 256 + w32);
                }
#pragma unroll
                for (int nt = 0; nt < 4; ++nt) {
                    Bh[nt] = *(const bf16x8*)(hb + (size_t)nt * 16 * EMBED + ko);
                    Bl[nt] = *(const bf16x8*)(lb + (size_t)nt * 16 * EMBED + ko);
                }
#pragma unroll
                for (int mt = 0; mt < 4; ++mt)
#pragma unroll
                    for (int nt = 0; nt < 4; ++nt) {
                        acc[mt][nt] = __builtin_amdgcn_mfma_f32_16x16x32_bf16(Al[mt], Bh[nt], acc[mt][nt], 0, 0, 0);
                        acc[mt][nt] = __builtin_amdgcn_mfma_f32_16x16x32_bf16(Ah[mt], Bl[nt], acc[mt][nt], 0, 0, 0);
                        acc[mt][nt] = __builtin_amdgcn_mfma_f32_16x16x32_bf16(Ah[mt], Bh[nt], acc[mt][nt], 0, 0, 0);
                    }
            }

            if (ks != 0) {
                float* slab = smem + tsel * 12288 + (ks - 1) * 4096;
#pragma unroll
                for (int mt = 0; mt < 4; ++mt)
#pragma unroll
                    for (int nt = 0; nt < 4; ++nt)
#pragma unroll
                        for (int reg = 0; reg < 4; ++reg)
                            slab[((mt * 4 + nt) * 4 + reg) * 64 + lane] = acc[mt][nt][reg];
            }
            __syncthreads();
            if (ks == 0) {
                const float* slabs = smem + tsel * 12288;
#pragma unroll
                for (int mt = 0; mt < 4; ++mt)
#pragma unroll
                    for (int nt = 0; nt < 4; ++nt)
#pragma unroll
                        for (int reg = 0; reg < 4; ++reg) {
                            const int idx = ((mt * 4 + nt) * 4 + reg) * 64 + lane;
                            acc[mt][nt][reg] += slabs[idx] + slabs[4096 + idx] + slabs[8192 + idx];
                        }

                float bias[4];
#pragma unroll
                for (int nt = 0; nt < 4; ++nt) bias[nt] = b_fc[n0 + nt * 16 + r16];

#pragma unroll
                for (int mt = 0; mt < 4; ++mt)
#pragma unroll
                    for (int reg = 0; reg < 4; ++reg) {
                        const int row = mt * 16 + g * 4 + reg;
                        float* op = &out[(size_t)row * (MAXLEN * VOCAB) + (size_t)(t + 1) * VOCAB];
                        u64 km = 0ull;
#pragma unroll
                        for (int nt = 0; nt < 4; ++nt) {
                            const int col = n0 + nt * 16 + r16;
                            float v = acc[mt][nt][reg] + bias[nt];
                            __builtin_nontemporal_store(v, op + col);
                            u64 kk = pack_key(v, col);
                            km = kk > km ? kk : km;
                        }
#pragma unroll
                        for (int msk = 8; msk >= 1; msk >>= 1) {
                            u64 o = __shfl_xor(km, msk, 64);
                            km = km > o ? km : o;
                        }
                        if (r16 == 0) kredl[tsel * 64 + row] = km;
                    }
            }
            __syncthreads();
            if (w == 0) {
                const int row = lane;
                u64 k0 = kredl[row], k1 = kredl[64 + row];
                u64 km = k0 > k1 ? k0 : k1;
                __hip_atomic_fetch_max(kslab + (size_t)t * 1024 + row * 16, km,
                                       __ATOMIC_RELAXED, __HIP_MEMORY_SCOPE_AGENT);
            }
        }
        grid_barrier(barws, 2 + 2 * t, false);
    }
}

extern "C" void kernel_launch(void* const* d_in, const int* in_sizes, int n_in,
                              void* d_out, int out_size, void* d_ws, size_t ws_size,
                              hipStream_t stream) {
    const float* enc       = (const float*)d_in[0];
    const int*   captions  = (const int*)  d_in[1];
    const float* emb       = (const float*)d_in[2];
    const float* W_ih      = (const float*)d_in[3];
    const float* b_ih      = (const float*)d_in[4];
    const float* W_hh      = (const float*)d_in[5];
    const float* b_hh      = (const float*)d_in[6];
    const float* W_fc      = (const float*)d_in[7];
    const float* b_fc      = (const float*)d_in[8];
    const float* W_init_h  = (const float*)d_in[9];
    const float* b_init_h  = (const float*)d_in[10];
    const float* W_init_c  = (const float*)d_in[11];
    const float* b_init_c  = (const float*)d_in[12];
    float* out = (float*)d_out;

    char* wsb = (char*)d_ws;
    float*    cbuf  = (float*)(wsb + 0);           // 131072B
    u64*      kslab = (u64*)(wsb + 131072);        // 253952B -> ends 385024
    unsigned* barws = (unsigned*)(wsb + 393216);   // 135168B -> ends 528384
    unsigned* hhis  = (unsigned*)(wsb + 1048576);  // 32 x 65536B -> ends 3145728
    unsigned* hlos  = (unsigned*)(wsb + 3145728);  // 32 x 65536B -> ends 5242880
    unsigned* hxs   = (unsigned*)(wsb + 5242880);  // 32 x 65536B -> ends 7340032
    ushort_t* Whi   = (ushort_t*)(wsb + 7340032);  // 32768000B -> ends 40108032
    ushort_t* Wlo   = (ushort_t*)(wsb + 40108032); // 32768000B -> ends 72876032
    unsigned* barws_end = barws;  (void)barws_end;

    ws_init<<<132, 256, 0, stream>>>(barws, kslab);
    decode_all<<<NBLK, NTHR, 0, stream>>>(
        enc, captions, emb, W_ih, b_ih, W_hh, b_hh, W_fc, b_fc,
        W_init_h, b_init_h, W_init_c, b_init_c,
        out, cbuf, hhis, hlos, hxs, kslab, Whi, Wlo, barws);
}

// Round 18
// 2013.560 us; speedup vs baseline: 1.5321x; 1.5321x over previous
//
#include <hip/hip_runtime.h>
#include <stdint.h>

#define EMBED  512
#define HIDDEN 512
#define VOCAB  32000
#define BATCH  64
#define NPIX   196
#define MAXLEN 32
#define NBLK   256
#define NTHR   512
#define NGRP   16       // 16 groups x 16 blocks (barrier tree)

typedef float f32x4 __attribute__((ext_vector_type(4)));
typedef short bf16x8 __attribute__((ext_vector_type(8)));
typedef unsigned short ushort_t;
typedef unsigned long long u64;

// ---------- helpers ----------
__device__ __forceinline__ u64 pack_key(float v, int idx) {
    unsigned u = __float_as_uint(v);
    u = (u & 0x80000000u) ? ~u : (u | 0x80000000u);   // monotone sortable map
    return ((u64)u << 32) | (unsigned)(~(unsigned)idx); // smaller idx wins ties
}
__device__ __forceinline__ ushort_t f2bf(float x) {           // round-to-nearest-even
    unsigned u = __float_as_uint(x);
    unsigned r = (u + 0x7fffu + ((u >> 16) & 1u)) >> 16;
    return (ushort_t)r;
}
__device__ __forceinline__ float bf2f(ushort_t h) {
    return __uint_as_float(((unsigned)h) << 16);
}
__device__ __forceinline__ void cst32(unsigned* p, unsigned v) {
    __hip_atomic_store(p, v, __ATOMIC_RELAXED, __HIP_MEMORY_SCOPE_AGENT);
}
__device__ __forceinline__ u64 cld64(const u64* p) {
    return __hip_atomic_load(p, __ATOMIC_RELAXED, __HIP_MEMORY_SCOPE_AGENT);
}

// ---------- tree grid barrier (R10-proven; R14 backoff) ----------
__device__ __forceinline__ void grid_barrier(unsigned* barws, int k, bool fence) {
    __syncthreads();
    if (threadIdx.x == 0) {
        const int grp = blockIdx.x >> 4;
        const bool leader = (blockIdx.x & 15) == 0;
        unsigned* gc = barws + (k * NGRP + grp) * 16;
        unsigned* rc = barws + 16384 + k * 16;
        unsigned* gf = barws + 17408 + (k * NGRP + grp) * 16;
        if (fence) __threadfence();
        else asm volatile("s_waitcnt vmcnt(0)" ::: "memory");
        if (!leader) {
            __hip_atomic_fetch_add(gc, 1u, __ATOMIC_RELAXED, __HIP_MEMORY_SCOPE_AGENT);
            while (__hip_atomic_fetch_add(gf, 0u, __ATOMIC_RELAXED, __HIP_MEMORY_SCOPE_AGENT) == 0u)
                __builtin_amdgcn_s_sleep(32);
        } else {
            while (__hip_atomic_fetch_add(gc, 0u, __ATOMIC_RELAXED, __HIP_MEMORY_SCOPE_AGENT) < 15u)
                __builtin_amdgcn_s_sleep(8);
            __hip_atomic_fetch_add(rc, 1u, __ATOMIC_RELAXED, __HIP_MEMORY_SCOPE_AGENT);
            while (__hip_atomic_fetch_add(rc, 0u, __ATOMIC_RELAXED, __HIP_MEMORY_SCOPE_AGENT) < (unsigned)NGRP)
                __builtin_amdgcn_s_sleep(8);
            __hip_atomic_fetch_add(gf, 1u, __ATOMIC_RELAXED, __HIP_MEMORY_SCOPE_AGENT);
        }
        asm volatile("" ::: "memory");
    }
    __syncthreads();
}

__global__ void ws_init(unsigned* barws, u64* kslab) {
    const int i = blockIdx.x * 256 + threadIdx.x;
    if (i < 33792) barws[i] = 0u;
    if (i < 31 * 1024) kslab[i] = 0ull;      // 31 steps x 64 rows x 16-u64 stride
}

// ---------- the whole decode, one persistent kernel ----------
// lstm: R15-verified (LDS-staged VALU, padded banks). fc: per-wave full-K
// 16-col strip — no split-K, no LDS dump, clean 16-iter pipelined loop.
__global__ __launch_bounds__(512, 2) void decode_all(
    const float* __restrict__ enc,
    const int*   __restrict__ captions,
    const float* __restrict__ emb,
    const float* __restrict__ W_ih, const float* __restrict__ b_ih,
    const float* __restrict__ W_hh, const float* __restrict__ b_hh,
    const float* __restrict__ W_fc, const float* __restrict__ b_fc,
    const float* __restrict__ W_init_h, const float* __restrict__ b_init_h,
    const float* __restrict__ W_init_c, const float* __restrict__ b_init_c,
    float* __restrict__ out,
    float* __restrict__ cbuf,       // block-owned units after fenced init
    float* __restrict__ hfs,        // [32][64][512] f32 h slabs (slab t = input to step t)
    unsigned* __restrict__ hhis,    // [31][64][256] packed 2xbf16 hi slabs
    unsigned* __restrict__ hlos,    // [31][64][256] packed 2xbf16 lo slabs
    u64* __restrict__ kslab,        // [31][64][16] argmax keys (pre-zeroed)
    ushort_t* __restrict__ Whi, ushort_t* __restrict__ Wlo,
    unsigned* __restrict__ barws)
{
    __shared__ float wlds[8 * 1032];                  // 33 KB persistent lstm W (padded)
    __shared__ __align__(16) float smem[8448];        // lstm h-stage / init summary
    __shared__ u64 kredl[512];                        // fc per-wave row maxes

    const int blk = blockIdx.x, tid = threadIdx.x;
    const int lane = tid & 63, w = tid >> 6;
    const int u0 = blk * 2;
    const int r16 = lane & 15, g = lane >> 4;

    // ---- one-time: lstm W rows -> LDS (padded stride 1032) ----
    for (int i = tid; i < 8192; i += NTHR) {
        const int rowp = i >> 10, off = i & 1023;     // rowp = uu*4+q
        const int uu = rowp >> 2, q = rowp & 3;
        const int j = q * HIDDEN + u0 + uu;
        wlds[rowp * 1032 + off] = (off < 512) ? W_ih[(size_t)j * 512 + off]
                                              : W_hh[(size_t)j * 512 + off - 512];
    }

    // ---- one-time: wsplit W_fc -> Whi/Wlo ----
    {
        const int nt4 = VOCAB * EMBED / 4;
        for (int i = blk * NTHR + tid; i < nt4; i += NBLK * NTHR) {
            f32x4 wv = ((const f32x4*)W_fc)[i];
            ushort_t hi[4], lo[4];
#pragma unroll
            for (int e = 0; e < 4; ++e) {
                hi[e] = f2bf(wv[e]);
                lo[e] = f2bf(wv[e] - bf2f(hi[e]));
            }
            *(uint64_t*)&Whi[i * 4] = *(const uint64_t*)hi;
            *(uint64_t*)&Wlo[i * 4] = *(const uint64_t*)lo;
        }
    }

    // ---- one-time: init (blocks 0..63) ----
    if (blk < BATCH) {
        const int b = blk;
        {
            float s = 0.f;
            const float* p = enc + (size_t)b * NPIX * HIDDEN + tid;
            for (int px = 0; px < NPIX; ++px) s += p[(size_t)px * HIDDEN];
            smem[tid] = s * (1.0f / NPIX);
        }
        __syncthreads();
        {
            const int j = tid;
            const f32x4* wh = (const f32x4*)(W_init_h + (size_t)j * HIDDEN);
            const f32x4* wc = (const f32x4*)(W_init_c + (size_t)j * HIDDEN);
            float ah = 0.f, ac = 0.f;
            for (int k4 = 0; k4 < HIDDEN / 4; ++k4) {
                f32x4 s4 = *(const f32x4*)&smem[k4 * 4];
                f32x4 a = wh[k4], cc = wc[k4];
                ah += s4[0]*a[0] + s4[1]*a[1] + s4[2]*a[2] + s4[3]*a[3];
                ac += s4[0]*cc[0] + s4[1]*cc[1] + s4[2]*cc[2] + s4[3]*cc[3];
            }
            hfs[b * HIDDEN + j] = ah + b_init_h[j];          // slab 0, plain (fenced bar)
            cbuf[b * HIDDEN + j] = ac + b_init_c[j];
        }
        f32x4* o4 = (f32x4*)(out + (size_t)b * MAXLEN * VOCAB);
        f32x4 z = {0.f, 0.f, 0.f, 0.f};
        for (int i = tid; i < VOCAB / 4; i += NTHR) __builtin_nontemporal_store(z, &o4[i]);
    }
    grid_barrier(barws, 0, true);

    // ======== 31 decode steps ========
    for (int t = 0; t < MAXLEN - 1; ++t) {
        const float* hfin  = hfs + (size_t)t * 32768;        // slab t (read-only now)
        unsigned*    hfout = (unsigned*)(hfs + (size_t)(t + 1) * 32768);
        const unsigned* hhi_t = hhis + (size_t)t * 16384;
        const unsigned* hlo_t = hlos + (size_t)t * 16384;

        // ---------- LSTM phase (all blocks; units u0, u0+1) — R15-verified ----------
        {
            const int b = tid >> 3, r = tid & 7, uu = r >> 2, q = r & 3;
            const int rowp = uu * 4 + q;
            const int j = q * HIDDEN + u0 + uu;

            int tok;
            if (t == 0) tok = captions[b * MAXLEN];
            else {
                u64 km = cld64(kslab + (size_t)(t - 1) * 1024 + b * 16);
                tok = (int)(~(unsigned)(km & 0xffffffffull));
            }

            const f32x4* x4 = (const f32x4*)(emb + (size_t)tok * EMBED);
            const f32x4* wih4 = (const f32x4*)(wlds + rowp * 1032);
            const f32x4* whh4 = wih4 + 128;

            float a = 0.f;
            const int hr = tid >> 3, hc = (tid & 7) * 16;   // stage mapping
            for (int c = 0; c < 4; ++c) {          // 128-col h chunks, rows padded 132
                __syncthreads();
                {
                    const f32x4* gp = (const f32x4*)(hfin + (size_t)hr * HIDDEN + c * 128 + hc);
                    f32x4 h0 = gp[0], h1 = gp[1], h2 = gp[2], h3 = gp[3];
                    float* lp = &smem[hr * 132 + hc];
                    *(f32x4*)(lp)      = h0;
                    *(f32x4*)(lp + 4)  = h1;
                    *(f32x4*)(lp + 8)  = h2;
                    *(f32x4*)(lp + 12) = h3;
                }
                __syncthreads();
                const float* hs = smem + b * 132;
#pragma unroll 4
                for (int k4 = 0; k4 < 32; ++k4) {
                    const int kg = c * 32 + k4;
                    f32x4 xv = x4[kg];
                    f32x4 hv = *(const f32x4*)&hs[k4 * 4];
                    f32x4 wA = wih4[kg], vA = whh4[kg];
                    a += xv[0]*wA[0] + xv[1]*wA[1] + xv[2]*wA[2] + xv[3]*wA[3]
                       + hv[0]*vA[0] + hv[1]*vA[1] + hv[2]*vA[2] + hv[3]*vA[3];
                }
            }
            a += b_ih[j] + b_hh[j];

            const int base = (lane & ~7) + uu * 4;
            float gi  = __shfl(a, base + 0, 64);
            float gfv = __shfl(a, base + 1, 64);
            float gg  = __shfl(a, base + 2, 64);
            float go  = __shfl(a, base + 3, 64);
            float i_ = 1.f / (1.f + expf(-gi));
            float f_ = 1.f / (1.f + expf(-gfv));
            float o_ = 1.f / (1.f + expf(-go));
            float g_ = tanhf(gg);
            float cv = cbuf[b * HIDDEN + u0 + uu];
            float c2 = f_ * cv + i_ * g_;
            float h2 = o_ * tanhf(c2);
            if (q == 0) cbuf[b * HIDDEN + u0 + uu] = c2;
            float h2o = __shfl(h2, (lane & ~7) + 4, 64);   // uu=1 value
            if (r == 0) {
                ushort_t h0h = f2bf(h2),             h1h = f2bf(h2o);
                ushort_t h0l = f2bf(h2 - bf2f(h0h)), h1l = f2bf(h2o - bf2f(h1h));
                cst32((unsigned*)hhis + (size_t)t * 16384 + ((b * HIDDEN + u0) >> 1),
                      (unsigned)h0h | ((unsigned)h1h << 16));
                cst32((unsigned*)hlos + (size_t)t * 16384 + ((b * HIDDEN + u0) >> 1),
                      (unsigned)h0l | ((unsigned)h1l << 16));
                cst32(hfout + b * HIDDEN + u0,     __float_as_uint(h2));
                cst32(hfout + b * HIDDEN + u0 + 1, __float_as_uint(h2o));
            }
        }
        grid_barrier(barws, 1 + 2 * t, false);

        // ---------- FC phase: per-wave full-K 16-col strip (blocks 0..249) ----------
        if (blk < 250) {
            const int n0w = blk * 128 + w * 16;        // this wave's column strip
            const int col = n0w + r16;                 // this lane's column

            f32x4 acc[4];
#pragma unroll
            for (int i = 0; i < 4; ++i) acc[i] = (f32x4){0.f, 0.f, 0.f, 0.f};

            const ushort_t* hb = Whi + (size_t)col * EMBED + g * 8;
            const ushort_t* lb = Wlo + (size_t)col * EMBED + g * 8;

            // software-pipelined B (W) stream: prefetch next kb during MFMA
            bf16x8 Bh = *(const bf16x8*)(hb);
            bf16x8 Bl = *(const bf16x8*)(lb);
#pragma unroll
            for (int kb = 0; kb < 16; ++kb) {
                const int w32 = kb * 16 + g * 4;       // u32 index of A-frag
                bf16x8 Ah[4], Al[4];
#pragma unroll
                for (int mt = 0; mt < 4; ++mt) {
                    Ah[mt] = *(const bf16x8*)(hhi_t + (size_t)(mt * 16 + r16) * 256 + w32);
                    Al[mt] = *(const bf16x8*)(hlo_t + (size_t)(mt * 16 + r16) * 256 + w32);
                }
                bf16x8 Bh_n = Bh, Bl_n = Bl;
                if (kb < 15) {
                    Bh_n = *(const bf16x8*)(hb + (kb + 1) * 32);
                    Bl_n = *(const bf16x8*)(lb + (kb + 1) * 32);
                }
#pragma unroll
                for (int mt = 0; mt < 4; ++mt) {
                    acc[mt] = __builtin_amdgcn_mfma_f32_16x16x32_bf16(Al[mt], Bh, acc[mt], 0, 0, 0);
                    acc[mt] = __builtin_amdgcn_mfma_f32_16x16x32_bf16(Ah[mt], Bl, acc[mt], 0, 0, 0);
                    acc[mt] = __builtin_amdgcn_mfma_f32_16x16x32_bf16(Ah[mt], Bh, acc[mt], 0, 0, 0);
                }
                Bh = Bh_n; Bl = Bl_n;
            }

            // epilogue: bias, NT store, per-row max over the 16-lane col group
            const float bias = b_fc[col];
#pragma unroll
            for (int mt = 0; mt < 4; ++mt) {
                u64 rowkey[4];
#pragma unroll
                for (int reg = 0; reg < 4; ++reg) {
                    const int row = mt * 16 + g * 4 + reg;
                    float v = acc[mt][reg] + bias;
                    __builtin_nontemporal_store(v,
                        &out[(size_t)row * (MAXLEN * VOCAB) + (size_t)(t + 1) * VOCAB + col]);
                    u64 km = pack_key(v, col);
#pragma unroll
                    for (int msk = 8; msk >= 1; msk >>= 1) {
                        u64 o = __shfl_xor(km, msk, 64);
                        km = km > o ? km : o;
                    }
                    rowkey[reg] = km;
                }
                if (r16 == 0) {
#pragma unroll
                    for (int reg = 0; reg < 4; ++reg)
                        kredl[w * 64 + mt * 16 + g * 4 + reg] = rowkey[reg];
                }
            }
            __syncthreads();
            if (w == 0) {   // merge 8 wave-strips, one fetch_max per row line
                const int row = lane;
                u64 km = kredl[row];
#pragma unroll
                for (int jj = 1; jj < 8; ++jj) {
                    u64 k = kredl[jj * 64 + row];
                    km = k > km ? k : km;
                }
                __hip_atomic_fetch_max(kslab + (size_t)t * 1024 + row * 16, km,
                                       __ATOMIC_RELAXED, __HIP_MEMORY_SCOPE_AGENT);
            }
        }
        grid_barrier(barws, 2 + 2 * t, false);
    }
}

extern "C" void kernel_launch(void* const* d_in, const int* in_sizes, int n_in,
                              void* d_out, int out_size, void* d_ws, size_t ws_size,
                              hipStream_t stream) {
    const float* enc       = (const float*)d_in[0];
    const int*   captions  = (const int*)  d_in[1];
    const float* emb       = (const float*)d_in[2];
    const float* W_ih      = (const float*)d_in[3];
    const float* b_ih      = (const float*)d_in[4];
    const float* W_hh      = (const float*)d_in[5];
    const float* b_hh      = (const float*)d_in[6];
    const float* W_fc      = (const float*)d_in[7];
    const float* b_fc      = (const float*)d_in[8];
    const float* W_init_h  = (const float*)d_in[9];
    const float* b_init_h  = (const float*)d_in[10];
    const float* W_init_c  = (const float*)d_in[11];
    const float* b_init_c  = (const float*)d_in[12];
    float* out = (float*)d_out;

    char* wsb = (char*)d_ws;
    float*    cbuf  = (float*)(wsb + 0);           // 131072B
    u64*      kslab = (u64*)(wsb + 131072);        // 253952B -> ends 385024
    unsigned* barws = (unsigned*)(wsb + 393216);   // 135168B -> ends 528384
    float*    hfs   = (float*)(wsb + 1048576);     // 32 x 131072B -> ends 5242880
    unsigned* hhis  = (unsigned*)(wsb + 5242880);  // 31 x 65536B -> ends 7274496
    unsigned* hlos  = (unsigned*)(wsb + 7274496);  // 31 x 65536B -> ends 9306112
    ushort_t* Whi   = (ushort_t*)(wsb + 9437184);  // 32768000B -> ends 42205184
    ushort_t* Wlo   = (ushort_t*)(wsb + 42205184); // 32768000B -> ends 74973184

    ws_init<<<132, 256, 0, stream>>>(barws, kslab);
    decode_all<<<NBLK, NTHR, 0, stream>>>(
        enc, captions, emb, W_ih, b_ih, W_hh, b_hh, W_fc, b_fc,
        W_init_h, b_init_h, W_init_c, b_init_c,
        out, cbuf, hfs, hhis, hlos, kslab, Whi, Wlo, barws);
}

// Round 19
// 1216.297 us; speedup vs baseline: 2.5364x; 1.6555x over previous
//
#include <hip/hip_runtime.h>
#include <stdint.h>

#define EMBED  512
#define HIDDEN 512
#define VOCAB  32000
#define BATCH  64
#define NPIX   196
#define MAXLEN 32
#define NBLK   256
#define NTHR   512
#define NGRP   16       // 16 groups x 16 blocks (barrier tree)

typedef float f32x4 __attribute__((ext_vector_type(4)));
typedef short bf16x8 __attribute__((ext_vector_type(8)));
typedef unsigned short ushort_t;
typedef unsigned long long u64;

// ---------- helpers ----------
__device__ __forceinline__ u64 pack_key(float v, int idx) {
    unsigned u = __float_as_uint(v);
    u = (u & 0x80000000u) ? ~u : (u | 0x80000000u);   // monotone sortable map
    return ((u64)u << 32) | (unsigned)(~(unsigned)idx); // smaller idx wins ties
}
__device__ __forceinline__ ushort_t f2bf(float x) {           // round-to-nearest-even
    unsigned u = __float_as_uint(x);
    unsigned r = (u + 0x7fffu + ((u >> 16) & 1u)) >> 16;
    return (ushort_t)r;
}
__device__ __forceinline__ float bf2f(ushort_t h) {
    return __uint_as_float(((unsigned)h) << 16);
}
__device__ __forceinline__ void cst32(unsigned* p, unsigned v) {
    __hip_atomic_store(p, v, __ATOMIC_RELAXED, __HIP_MEMORY_SCOPE_AGENT);
}
__device__ __forceinline__ u64 cld64(const u64* p) {
    return __hip_atomic_load(p, __ATOMIC_RELAXED, __HIP_MEMORY_SCOPE_AGENT);
}

// ---------- tree grid barrier (R10-proven; R14 backoff) ----------
__device__ __forceinline__ void grid_barrier(unsigned* barws, int k, bool fence) {
    __syncthreads();
    if (threadIdx.x == 0) {
        const int grp = blockIdx.x >> 4;
        const bool leader = (blockIdx.x & 15) == 0;
        unsigned* gc = barws + (k * NGRP + grp) * 16;
        unsigned* rc = barws + 16384 + k * 16;
        unsigned* gf = barws + 17408 + (k * NGRP + grp) * 16;
        if (fence) __threadfence();
        else asm volatile("s_waitcnt vmcnt(0)" ::: "memory");
        if (!leader) {
            __hip_atomic_fetch_add(gc, 1u, __ATOMIC_RELAXED, __HIP_MEMORY_SCOPE_AGENT);
            while (__hip_atomic_fetch_add(gf, 0u, __ATOMIC_RELAXED, __HIP_MEMORY_SCOPE_AGENT) == 0u)
                __builtin_amdgcn_s_sleep(32);
        } else {
            while (__hip_atomic_fetch_add(gc, 0u, __ATOMIC_RELAXED, __HIP_MEMORY_SCOPE_AGENT) < 15u)
                __builtin_amdgcn_s_sleep(8);
            __hip_atomic_fetch_add(rc, 1u, __ATOMIC_RELAXED, __HIP_MEMORY_SCOPE_AGENT);
            while (__hip_atomic_fetch_add(rc, 0u, __ATOMIC_RELAXED, __HIP_MEMORY_SCOPE_AGENT) < (unsigned)NGRP)
                __builtin_amdgcn_s_sleep(8);
            __hip_atomic_fetch_add(gf, 1u, __ATOMIC_RELAXED, __HIP_MEMORY_SCOPE_AGENT);
        }
        asm volatile("" ::: "memory");
    }
    __syncthreads();
}

__global__ void ws_init(unsigned* barws, u64* kslab) {
    const int i = blockIdx.x * 256 + threadIdx.x;
    if (i < 33792) barws[i] = 0u;
    if (i < 31 * 1024) kslab[i] = 0ull;      // 31 steps x 64 rows x 16-u64 stride
}

// ---------- the whole decode, one persistent kernel ----------
// fc W and h stored in MFMA-FRAGMENT ORDER: every load is one coalesced
// 1KB wave-transaction (vs 64-way scattered 16B in R18).
__global__ __launch_bounds__(512, 2) void decode_all(
    const float* __restrict__ enc,
    const int*   __restrict__ captions,
    const float* __restrict__ emb,
    const float* __restrict__ W_ih, const float* __restrict__ b_ih,
    const float* __restrict__ W_hh, const float* __restrict__ b_hh,
    const float* __restrict__ W_fc, const float* __restrict__ b_fc,
    const float* __restrict__ W_init_h, const float* __restrict__ b_init_h,
    const float* __restrict__ W_init_c, const float* __restrict__ b_init_c,
    float* __restrict__ out,
    float* __restrict__ cbuf,       // block-owned units after fenced init
    float* __restrict__ hfs,        // [32][64][512] f32 h slabs (slab t = input to step t)
    unsigned* __restrict__ hhis,    // [31][16384] u32 — HPK fragment-packed hi
    unsigned* __restrict__ hlos,    // [31][16384] u32 — HPK fragment-packed lo
    u64* __restrict__ kslab,        // [31][64][16] argmax keys (pre-zeroed)
    ushort_t* __restrict__ Whi, ushort_t* __restrict__ Wlo,   // WPK fragment-packed
    unsigned* __restrict__ barws)
{
    __shared__ float wlds[8 * 1032];                  // 33 KB persistent lstm W (padded)
    __shared__ __align__(16) float smem[8448];        // lstm h-stage / init summary
    __shared__ u64 kredl[512];                        // fc per-wave row maxes

    const int blk = blockIdx.x, tid = threadIdx.x;
    const int lane = tid & 63, w = tid >> 6;
    const int u0 = blk * 2;
    const int r16 = lane & 15, g = lane >> 4;

    // ---- one-time: lstm W rows -> LDS (padded stride 1032) ----
    for (int i = tid; i < 8192; i += NTHR) {
        const int rowp = i >> 10, off = i & 1023;     // rowp = uu*4+q
        const int uu = rowp >> 2, q = rowp & 3;
        const int j = q * HIDDEN + u0 + uu;
        wlds[rowp * 1032 + off] = (off < 512) ? W_ih[(size_t)j * 512 + off]
                                              : W_hh[(size_t)j * 512 + off - 512];
    }

    // ---- one-time: wsplit W_fc -> WPK fragment-packed Whi/Wlo ----
    // fragment i: col = i>>6, kf = i&63 (k0 = kf*8); kb = kf>>2, gw = kf&3.
    // dst frag = ((col>>7)*8 + ((col>>4)&7))*16 + kb)*64 + gw*16 + (col&15).
    {
        const int nfrag = VOCAB * 64;
        for (int i = blk * NTHR + tid; i < nfrag; i += NBLK * NTHR) {
            const int col = i >> 6, kf = i & 63;
            const int kb = kf >> 2, gw = kf & 3;
            const f32x4* src = (const f32x4*)(W_fc + (size_t)col * EMBED + kf * 8);
            f32x4 w0 = src[0], w1 = src[1];
            ushort_t hi[8], lo[8];
#pragma unroll
            for (int e = 0; e < 4; ++e) {
                hi[e] = f2bf(w0[e]);     lo[e] = f2bf(w0[e] - bf2f(hi[e]));
                hi[4+e] = f2bf(w1[e]);   lo[4+e] = f2bf(w1[e] - bf2f(hi[4+e]));
            }
            const size_t d = ((size_t)(((col >> 7) * 8 + ((col >> 4) & 7)) * 16 + kb) * 64
                              + gw * 16 + (col & 15)) * 8;
            *(uint64_t*)&Whi[d]     = *(const uint64_t*)hi;
            *(uint64_t*)&Whi[d + 4] = *(const uint64_t*)(hi + 4);
            *(uint64_t*)&Wlo[d]     = *(const uint64_t*)lo;
            *(uint64_t*)&Wlo[d + 4] = *(const uint64_t*)(lo + 4);
        }
    }

    // ---- one-time: init (blocks 0..63) ----
    if (blk < BATCH) {
        const int b = blk;
        {
            float s = 0.f;
            const float* p = enc + (size_t)b * NPIX * HIDDEN + tid;
            for (int px = 0; px < NPIX; ++px) s += p[(size_t)px * HIDDEN];
            smem[tid] = s * (1.0f / NPIX);
        }
        __syncthreads();
        {
            const int j = tid;
            const f32x4* wh = (const f32x4*)(W_init_h + (size_t)j * HIDDEN);
            const f32x4* wc = (const f32x4*)(W_init_c + (size_t)j * HIDDEN);
            float ah = 0.f, ac = 0.f;
            for (int k4 = 0; k4 < HIDDEN / 4; ++k4) {
                f32x4 s4 = *(const f32x4*)&smem[k4 * 4];
                f32x4 a = wh[k4], cc = wc[k4];
                ah += s4[0]*a[0] + s4[1]*a[1] + s4[2]*a[2] + s4[3]*a[3];
                ac += s4[0]*cc[0] + s4[1]*cc[1] + s4[2]*cc[2] + s4[3]*cc[3];
            }
            ah += b_init_h[j];
            hfs[b * HIDDEN + j] = ah;                        // slab 0 f32 (fenced bar)
            cbuf[b * HIDDEN + j] = ac + b_init_c[j];
            // HPK slab-0 write: pair (j even, j+1) -> u32 col u2 = j>>1
            ushort_t hh = f2bf(ah), hl = f2bf(ah - bf2f(hh));
            unsigned packed = (unsigned)hh | ((unsigned)hl << 16);
            unsigned pp = __shfl_xor(packed, 1, 64);
            if ((j & 1) == 0) {
                const int u2 = j >> 1;                       // 0..255
                const int mt = b >> 4, r16m = b & 15;
                const int kb = u2 >> 4, tl = u2 & 15, gg2 = tl >> 2, jj = tl & 3;
                const size_t d = (size_t)(((kb * 4 + mt) * 64) + gg2 * 16 + r16m) * 4 + jj;
                hhis[d] = (packed & 0xffffu) | ((pp & 0xffffu) << 16);
                hlos[d] = (packed >> 16) | (pp & 0xffff0000u);
            }
        }
        f32x4* o4 = (f32x4*)(out + (size_t)b * MAXLEN * VOCAB);
        f32x4 z = {0.f, 0.f, 0.f, 0.f};
        for (int i = tid; i < VOCAB / 4; i += NTHR) __builtin_nontemporal_store(z, &o4[i]);
    }
    grid_barrier(barws, 0, true);

    // ======== 31 decode steps ========
    for (int t = 0; t < MAXLEN - 1; ++t) {
        const float* hfin  = hfs + (size_t)t * 32768;        // slab t (read-only now)
        unsigned*    hfout = (unsigned*)(hfs + (size_t)(t + 1) * 32768);
        const unsigned* hhi_t = hhis + (size_t)t * 16384;
        const unsigned* hlo_t = hlos + (size_t)t * 16384;

        // ---------- LSTM phase (all blocks; units u0, u0+1) — R15-verified ----------
        {
            const int b = tid >> 3, r = tid & 7, uu = r >> 2, q = r & 3;
            const int rowp = uu * 4 + q;
            const int j = q * HIDDEN + u0 + uu;

            int tok;
            if (t == 0) tok = captions[b * MAXLEN];
            else {
                u64 km = cld64(kslab + (size_t)(t - 1) * 1024 + b * 16);
                tok = (int)(~(unsigned)(km & 0xffffffffull));
            }

            const f32x4* x4 = (const f32x4*)(emb + (size_t)tok * EMBED);
            const f32x4* wih4 = (const f32x4*)(wlds + rowp * 1032);
            const f32x4* whh4 = wih4 + 128;

            float a = 0.f;
            const int hr = tid >> 3, hc = (tid & 7) * 16;   // stage mapping
            for (int c = 0; c < 4; ++c) {          // 128-col h chunks, rows padded 132
                __syncthreads();
                {
                    const f32x4* gp = (const f32x4*)(hfin + (size_t)hr * HIDDEN + c * 128 + hc);
                    f32x4 h0 = gp[0], h1 = gp[1], h2 = gp[2], h3 = gp[3];
                    float* lp = &smem[hr * 132 + hc];
                    *(f32x4*)(lp)      = h0;
                    *(f32x4*)(lp + 4)  = h1;
                    *(f32x4*)(lp + 8)  = h2;
                    *(f32x4*)(lp + 12) = h3;
                }
                __syncthreads();
                const float* hs = smem + b * 132;
#pragma unroll 4
                for (int k4 = 0; k4 < 32; ++k4) {
                    const int kg = c * 32 + k4;
                    f32x4 xv = x4[kg];
                    f32x4 hv = *(const f32x4*)&hs[k4 * 4];
                    f32x4 wA = wih4[kg], vA = whh4[kg];
                    a += xv[0]*wA[0] + xv[1]*wA[1] + xv[2]*wA[2] + xv[3]*wA[3]
                       + hv[0]*vA[0] + hv[1]*vA[1] + hv[2]*vA[2] + hv[3]*vA[3];
                }
            }
            a += b_ih[j] + b_hh[j];

            const int base = (lane & ~7) + uu * 4;
            float gi  = __shfl(a, base + 0, 64);
            float gfv = __shfl(a, base + 1, 64);
            float gg  = __shfl(a, base + 2, 64);
            float go  = __shfl(a, base + 3, 64);
            float i_ = 1.f / (1.f + expf(-gi));
            float f_ = 1.f / (1.f + expf(-gfv));
            float o_ = 1.f / (1.f + expf(-go));
            float g_ = tanhf(gg);
            float cv = cbuf[b * HIDDEN + u0 + uu];
            float c2 = f_ * cv + i_ * g_;
            float h2 = o_ * tanhf(c2);
            if (q == 0) cbuf[b * HIDDEN + u0 + uu] = c2;
            float h2o = __shfl(h2, (lane & ~7) + 4, 64);   // uu=1 value
            if (r == 0) {
                ushort_t h0h = f2bf(h2),             h1h = f2bf(h2o);
                ushort_t h0l = f2bf(h2 - bf2f(h0h)), h1l = f2bf(h2o - bf2f(h1h));
                // HPK write: u32 col u2 = blk, row b
                const int mt = b >> 4, r16m = b & 15;
                const int kb = blk >> 4, tl = blk & 15, gg2 = tl >> 2, jj = tl & 3;
                const size_t d = (size_t)(((kb * 4 + mt) * 64) + gg2 * 16 + r16m) * 4 + jj;
                cst32((unsigned*)hhis + (size_t)t * 16384 + d,
                      (unsigned)h0h | ((unsigned)h1h << 16));
                cst32((unsigned*)hlos + (size_t)t * 16384 + d,
                      (unsigned)h0l | ((unsigned)h1l << 16));
                cst32(hfout + b * HIDDEN + u0,     __float_as_uint(h2));
                cst32(hfout + b * HIDDEN + u0 + 1, __float_as_uint(h2o));
            }
        }
        grid_barrier(barws, 1 + 2 * t, false);

        // ---------- FC phase: per-wave full-K 16-col strip, coalesced frags ----------
        if (blk < 250) {
            const int col = blk * 128 + w * 16 + r16;   // this lane's column

            f32x4 acc[4];
#pragma unroll
            for (int i = 0; i < 4; ++i) acc[i] = (f32x4){0.f, 0.f, 0.f, 0.f};

            const ushort_t* wb_hi = Whi + ((size_t)(blk * 8 + w) * 16) * 64 * 8 + lane * 8;
            const ushort_t* wb_lo = Wlo + ((size_t)(blk * 8 + w) * 16) * 64 * 8 + lane * 8;

#pragma unroll
            for (int kb = 0; kb < 16; ++kb) {
                bf16x8 Bh = *(const bf16x8*)(wb_hi + (size_t)kb * 512);
                bf16x8 Bl = *(const bf16x8*)(wb_lo + (size_t)kb * 512);
                bf16x8 Ah[4], Al[4];
#pragma unroll
                for (int mt = 0; mt < 4; ++mt) {
                    const size_t d = (size_t)((kb * 4 + mt) * 64 + lane) * 4;
                    Ah[mt] = *(const bf16x8*)(hhi_t + d);
                    Al[mt] = *(const bf16x8*)(hlo_t + d);
                }
#pragma unroll
                for (int mt = 0; mt < 4; ++mt) {
                    acc[mt] = __builtin_amdgcn_mfma_f32_16x16x32_bf16(Al[mt], Bh, acc[mt], 0, 0, 0);
                    acc[mt] = __builtin_amdgcn_mfma_f32_16x16x32_bf16(Ah[mt], Bl, acc[mt], 0, 0, 0);
                    acc[mt] = __builtin_amdgcn_mfma_f32_16x16x32_bf16(Ah[mt], Bh, acc[mt], 0, 0, 0);
                }
            }

            // epilogue: bias, NT store, per-row max over the 16-lane col group
            const float bias = b_fc[col];
#pragma unroll
            for (int mt = 0; mt < 4; ++mt) {
                u64 rowkey[4];
#pragma unroll
                for (int reg = 0; reg < 4; ++reg) {
                    const int row = mt * 16 + g * 4 + reg;
                    float v = acc[mt][reg] + bias;
                    __builtin_nontemporal_store(v,
                        &out[(size_t)row * (MAXLEN * VOCAB) + (size_t)(t + 1) * VOCAB + col]);
                    u64 km = pack_key(v, col);
#pragma unroll
                    for (int msk = 8; msk >= 1; msk >>= 1) {
                        u64 o = __shfl_xor(km, msk, 64);
                        km = km > o ? km : o;
                    }
                    rowkey[reg] = km;
                }
                if (r16 == 0) {
#pragma unroll
                    for (int reg = 0; reg < 4; ++reg)
                        kredl[w * 64 + mt * 16 + g * 4 + reg] = rowkey[reg];
                }
            }
            __syncthreads();
            if (w == 0) {   // merge 8 wave-strips, one fetch_max per row line
                const int row = lane;
                u64 km = kredl[row];
#pragma unroll
                for (int jj = 1; jj < 8; ++jj) {
                    u64 k = kredl[jj * 64 + row];
                    km = k > km ? k : km;
                }
                __hip_atomic_fetch_max(kslab + (size_t)t * 1024 + row * 16, km,
                                       __ATOMIC_RELAXED, __HIP_MEMORY_SCOPE_AGENT);
            }
        }
        grid_barrier(barws, 2 + 2 * t, false);
    }
}

extern "C" void kernel_launch(void* const* d_in, const int* in_sizes, int n_in,
                              void* d_out, int out_size, void* d_ws, size_t ws_size,
                              hipStream_t stream) {
    const float* enc       = (const float*)d_in[0];
    const int*   captions  = (const int*)  d_in[1];
    const float* emb       = (const float*)d_in[2];
    const float* W_ih      = (const float*)d_in[3];
    const float* b_ih      = (const float*)d_in[4];
    const float* W_hh      = (const float*)d_in[5];
    const float* b_hh      = (const float*)d_in[6];
    const float* W_fc      = (const float*)d_in[7];
    const float* b_fc      = (const float*)d_in[8];
    const float* W_init_h  = (const float*)d_in[9];
    const float* b_init_h  = (const float*)d_in[10];
    const float* W_init_c  = (const float*)d_in[11];
    const float* b_init_c  = (const float*)d_in[12];
    float* out = (float*)d_out;

    char* wsb = (char*)d_ws;
    float*    cbuf  = (float*)(wsb + 0);           // 131072B
    u64*      kslab = (u64*)(wsb + 131072);        // 253952B -> ends 385024
    unsigned* barws = (unsigned*)(wsb + 393216);   // 135168B -> ends 528384
    float*    hfs   = (float*)(wsb + 1048576);     // 32 x 131072B -> ends 5242880
    unsigned* hhis  = (unsigned*)(wsb + 5242880);  // 31 x 65536B -> ends 7274496
    unsigned* hlos  = (unsigned*)(wsb + 7274496);  // 31 x 65536B -> ends 9306112
    ushort_t* Whi   = (ushort_t*)(wsb + 9437184);  // 32768000B -> ends 42205184
    ushort_t* Wlo   = (ushort_t*)(wsb + 42205184); // 32768000B -> ends 74973184

    ws_init<<<132, 256, 0, stream>>>(barws, kslab);
    decode_all<<<NBLK, NTHR, 0, stream>>>(
        enc, captions, emb, W_ih, b_ih, W_hh, b_hh, W_fc, b_fc,
        W_init_h, b_init_h, W_init_c, b_init_c,
        out, cbuf, hfs, hhis, hlos, kslab, Whi, Wlo, barws);
}